// Round 6
// baseline (51.723 us; speedup 1.0000x reference)
//
#include <hip/hip_runtime.h>

#define Bb 16
#define Ll 2048
#define Ee 256
#define E4 64
#define BPB 32          // kA blocks per batch (64 rows each)
#define RPB 64
#define JT 16           // kB blocks per batch (t f-slices)
#define FS (Ee / JT)
#define CBP 16          // kC blocks per batch (128 rows each)
#define CRP 128

// ws layout (floats). No zero-init needed: only active P1 slots are read,
// TP slots are always written, out is zeroed by kA each call.
#define P1_OFF 0                        // [16][32][256] row-sum partials
#define TP_OFF (P1_OFF + Bb*BPB*Ee)     // [16][16][256] t partials
#define C_OFF  (TP_OFF + Bb*JT*Ee)      // [16] c = s.bk

// kA: partial sums of valid rows -> P1[b][i][:]; block i==0 zeroes out[b,:]
__global__ void __launch_bounds__(256) kA(const float* __restrict__ x,
                                          const int* __restrict__ lengths,
                                          float* __restrict__ P1,
                                          float* __restrict__ out) {
    const int b = blockIdx.y, i = blockIdx.x;
    const int tid = threadIdx.x, lane = tid & 63, wid = tid >> 6;
    if (i == 0) out[b * Ee + tid] = 0.f;      // ordered before kC by dispatch
    const int len = lengths[b];
    const int r0 = i * RPB;
    if (r0 >= len) return;
    const int r1 = min(r0 + RPB, len);
    const float4* xb = (const float4*)(x + (size_t)b * Ll * Ee);
    float4 acc = {0.f, 0.f, 0.f, 0.f};
    for (int r = r0 + wid; r < r1; r += 4) {
        float4 v = xb[(size_t)r * E4 + lane];
        acc.x += v.x; acc.y += v.y; acc.z += v.z; acc.w += v.w;
    }
    __shared__ float4 part[256];
    part[tid] = acc;
    __syncthreads();
    if (tid < 64) {
        float4 a = part[tid], b1 = part[64+tid], c1 = part[128+tid], d1 = part[192+tid];
        float4 s4 = {a.x+b1.x+c1.x+d1.x, a.y+b1.y+c1.y+d1.y,
                     a.z+b1.z+c1.z+d1.z, a.w+b1.w+c1.w+d1.w};
        ((float4*)(P1 + ((size_t)(b * BPB + i)) * Ee))[tid] = s4;
    }
}

// kB: block (b,j): reduce P1 -> Xsum, full s (redundant per j), t-slice j.
// j==0 also emits C.
__global__ void __launch_bounds__(256) kB(const float* __restrict__ P1,
                                          const int* __restrict__ lengths,
                                          const float* __restrict__ Wq,
                                          const float* __restrict__ bq,
                                          const float* __restrict__ Wk,
                                          const float* __restrict__ bk,
                                          float* __restrict__ TP, float* __restrict__ C) {
    const int b = blockIdx.y, j = blockIdx.x;
    const int tid = threadIdx.x;
    const int len = lengths[b];
    const int nblk = (len + RPB - 1) / RPB;
    __shared__ alignas(16) float xs[Ee];
    __shared__ alignas(16) float s_sh[Ee];
    {
        float a = 0.f;
        for (int q = 0; q < nblk; ++q) a += P1[((size_t)(b * BPB + q)) * Ee + tid];
        xs[tid] = a;
    }
    __syncthreads();
    {
        const float4* wrow = (const float4*)(Wq + (size_t)tid * Ee);
        const float4* x4   = (const float4*)xs;
        float acc = 0.f;
#pragma unroll 8
        for (int q = 0; q < E4; ++q) {
            float4 w = wrow[q]; float4 v = x4[q];
            acc += w.x*v.x + w.y*v.y + w.z*v.z + w.w*v.w;
        }
        s_sh[tid] = acc + (float)len * bq[tid];
    }
    __syncthreads();
    float tp = 0.f;
#pragma unroll
    for (int f0 = 0; f0 < FS; ++f0) {
        const int f = j * FS + f0;
        tp += s_sh[f] * Wk[(size_t)f * Ee + tid];
    }
    TP[((size_t)(b * JT + j)) * Ee + tid] = tp;
    if (j == 0) {
        float p = s_sh[tid] * bk[tid];
#pragma unroll
        for (int m = 32; m; m >>= 1) p += __shfl_xor(p, m, 64);
        __shared__ float cred[4];
        if ((tid & 63) == 0) cred[tid >> 6] = p;
        __syncthreads();
        if (tid == 0) C[b] = cred[0] + cred[1] + cred[2] + cred[3];
    }
}

// kC: reduce t-partials -> tv; stream 128 rows (w = x.t + c); block-reduce
// partial u_i,w_i; project through Wv in-block; atomicAdd into out.
__global__ void __launch_bounds__(256) kC(const float* __restrict__ x,
                                          const int* __restrict__ lengths,
                                          const float* __restrict__ TP,
                                          const float* __restrict__ C,
                                          const float* __restrict__ Wv,
                                          const float* __restrict__ bv,
                                          float* __restrict__ out) {
    const int b = blockIdx.y, i = blockIdx.x;
    const int len = lengths[b];
    const int r0 = i * CRP;
    if (r0 >= len) return;                 // zero contribution
    const int r1 = min(r0 + CRP, len);
    const int tid = threadIdx.x, lane = tid & 63, wid = tid >> 6;

    const float4* tp4 = (const float4*)(TP + (size_t)b * JT * Ee);
    float4 tv = {0.f, 0.f, 0.f, 0.f};
#pragma unroll
    for (int jj = 0; jj < JT; ++jj) {
        float4 t = tp4[jj * E4 + lane];
        tv.x += t.x; tv.y += t.y; tv.z += t.z; tv.w += t.w;
    }
    const float cb = C[b];
    const float4* xb = (const float4*)(x + (size_t)b * Ll * Ee);
    float4 uacc = {0.f, 0.f, 0.f, 0.f};
    float wacc = 0.f;
    for (int r = r0 + wid; r < r1; r += 4) {
        float4 xv = xb[(size_t)r * E4 + lane];
        float d = xv.x*tv.x + xv.y*tv.y + xv.z*tv.z + xv.w*tv.w;
#pragma unroll
        for (int m = 32; m; m >>= 1) d += __shfl_xor(d, m, 64);
        float w = d + cb;
        uacc.x += w*xv.x; uacc.y += w*xv.y; uacc.z += w*xv.z; uacc.w += w*xv.w;
        wacc += w;                         // wave-uniform
    }
    __shared__ float4 part[256];
    __shared__ float cw[4];
    __shared__ alignas(16) float u_sh[Ee];
    __shared__ float w_sh;
    part[tid] = uacc;
    if (lane == 0) cw[wid] = wacc;
    __syncthreads();
    if (tid < 64) {
        float4 a = part[tid], b1 = part[64+tid], c1 = part[128+tid], d1 = part[192+tid];
        float4 s4 = {a.x+b1.x+c1.x+d1.x, a.y+b1.y+c1.y+d1.y,
                     a.z+b1.z+c1.z+d1.z, a.w+b1.w+c1.w+d1.w};
        ((float4*)u_sh)[tid] = s4;
    }
    if (tid == 0) w_sh = cw[0] + cw[1] + cw[2] + cw[3];
    __syncthreads();
    // out[b,e] += (Wv[e,:].u_i + bv[e]*w_i) / L   (linear in partials)
    const float4* wrow = (const float4*)(Wv + (size_t)tid * Ee);
    const float4* u4   = (const float4*)u_sh;
    float acc = 0.f;
#pragma unroll 8
    for (int q = 0; q < E4; ++q) {
        float4 w = wrow[q]; float4 v = u4[q];
        acc += w.x*v.x + w.y*v.y + w.z*v.z + w.w*v.w;
    }
    atomicAdd(out + b * Ee + tid, (acc + bv[tid] * w_sh) * (1.0f / (float)Ll));
}

extern "C" void kernel_launch(void* const* d_in, const int* in_sizes, int n_in,
                              void* d_out, int out_size, void* d_ws, size_t ws_size,
                              hipStream_t stream) {
    const float* x       = (const float*)d_in[0];
    const int*   lengths = (const int*)d_in[1];
    const float* Wq      = (const float*)d_in[2];
    const float* bq      = (const float*)d_in[3];
    const float* Wk      = (const float*)d_in[4];
    const float* bk      = (const float*)d_in[5];
    const float* Wv      = (const float*)d_in[6];
    const float* bv      = (const float*)d_in[7];
    float* out = (float*)d_out;
    float* ws  = (float*)d_ws;

    kA<<<dim3(BPB, Bb), 256, 0, stream>>>(x, lengths, ws + P1_OFF, out);
    kB<<<dim3(JT, Bb), 256, 0, stream>>>(ws + P1_OFF, lengths, Wq, bq, Wk, bk,
                                         ws + TP_OFF, ws + C_OFF);
    kC<<<dim3(CBP, Bb), 256, 0, stream>>>(x, lengths, ws + TP_OFF, ws + C_OFF,
                                          Wv, bv, out);
}

// Round 7
// 50.618 us; speedup vs baseline: 1.0218x; 1.0218x over previous
//
#include <hip/hip_runtime.h>

#define Bb 16
#define Ll 2048
#define Ee 256
#define E4 64
#define BPB 32          // P1 blocks per batch (64 rows each)
#define RPB 64
#define CBP 16          // kMain blocks per batch (128 rows each)
#define CRP 128

// ws layout (floats). No zero-init needed: only active P1 slots are read;
// M/bqk/kvec/beta always fully written by kPrep; out zeroed by kPrep.
#define P1_OFF 0                        // [16][32][256] row-sum partials
#define M_OFF  (P1_OFF + Bb*BPB*Ee)     // [256][256] M = Wq^T Wk
#define BQK_OFF (M_OFF + Ee*Ee)         // [256] bqk = bq @ Wk
#define KV_OFF  (BQK_OFF + Ee)          // [256] kvec = Wq^T bk
#define BETA_OFF (KV_OFF + Ee)          // [1]   beta = bq.bk

// kPrep: blocks [0,512): P1 partials (i==0 zeroes out[b,:]).
//        blocks [512,768): row ep of M = Wq^T Wk; kvec[ep]; ep==0 also bqk, beta.
__global__ void __launch_bounds__(256) kPrep(const float* __restrict__ x,
                                             const int* __restrict__ lengths,
                                             const float* __restrict__ Wq,
                                             const float* __restrict__ bq,
                                             const float* __restrict__ Wk,
                                             const float* __restrict__ bk,
                                             float* __restrict__ ws,
                                             float* __restrict__ out) {
    const int blk = blockIdx.x;
    const int tid = threadIdx.x, lane = tid & 63, wid = tid >> 6;

    if (blk < Bb * BPB) {
        // ---- P1 role ----
        const int b = blk >> 5, i = blk & 31;
        if (i == 0) out[b * Ee + tid] = 0.f;
        const int len = lengths[b];
        const int r0 = i * RPB;
        if (r0 >= len) return;
        const int r1 = min(r0 + RPB, len);
        const float4* xb = (const float4*)(x + (size_t)b * Ll * Ee);
        float4 acc = {0.f, 0.f, 0.f, 0.f};
        for (int r = r0 + wid; r < r1; r += 4) {
            float4 v = xb[(size_t)r * E4 + lane];
            acc.x += v.x; acc.y += v.y; acc.z += v.z; acc.w += v.w;
        }
        __shared__ float4 part[256];
        part[tid] = acc;
        __syncthreads();
        if (tid < 64) {
            float4 a = part[tid], b1 = part[64+tid], c1 = part[128+tid], d1 = part[192+tid];
            float4 s4 = {a.x+b1.x+c1.x+d1.x, a.y+b1.y+c1.y+d1.y,
                         a.z+b1.z+c1.z+d1.z, a.w+b1.w+c1.w+d1.w};
            ((float4*)(ws + P1_OFF + ((size_t)(b * BPB + i)) * Ee))[tid] = s4;
        }
        return;
    }

    // ---- M role: row ep ----
    const int ep = blk - Bb * BPB;
    const float4* wk4 = (const float4*)Wk;
    float4 macc = {0.f, 0.f, 0.f, 0.f};
    float4 qacc = {0.f, 0.f, 0.f, 0.f};   // bqk partials (block ep==0 only uses)
    const bool doBqk = (ep == 0);
#pragma unroll 8
    for (int q = 0; q < 64; ++q) {
        const int f = wid * 64 + q;
        const float wq = Wq[(size_t)f * Ee + ep];   // broadcast load
        const float4 w4 = wk4[(size_t)f * E4 + lane];
        macc.x += wq * w4.x; macc.y += wq * w4.y;
        macc.z += wq * w4.z; macc.w += wq * w4.w;
        if (doBqk) {
            const float bqf = bq[f];
            qacc.x += bqf * w4.x; qacc.y += bqf * w4.y;
            qacc.z += bqf * w4.z; qacc.w += bqf * w4.w;
        }
    }
    // kvec[ep] partial: lane l of wave wid covers f = wid*64 + l
    float kv = Wq[(size_t)(wid * 64 + lane) * Ee + ep] * bk[wid * 64 + lane];
#pragma unroll
    for (int m = 32; m; m >>= 1) kv += __shfl_xor(kv, m, 64);

    __shared__ float4 mred[4][64];
    __shared__ float4 qred[4][64];
    __shared__ float kred[4];
    mred[wid][lane] = macc;
    if (doBqk) qred[wid][lane] = qacc;
    if (lane == 0) kred[wid] = kv;
    __syncthreads();
    if (wid == 0) {
        float4 a = mred[0][lane], b1 = mred[1][lane], c1 = mred[2][lane], d1 = mred[3][lane];
        float4 s4 = {a.x+b1.x+c1.x+d1.x, a.y+b1.y+c1.y+d1.y,
                     a.z+b1.z+c1.z+d1.z, a.w+b1.w+c1.w+d1.w};
        ((float4*)(ws + M_OFF + (size_t)ep * Ee))[lane] = s4;
        if (lane == 0) ws[KV_OFF + ep] = kred[0] + kred[1] + kred[2] + kred[3];
    }
    if (doBqk) {
        if (wid == 1) {
            float4 a = qred[0][lane], b1 = qred[1][lane], c1 = qred[2][lane], d1 = qred[3][lane];
            float4 s4 = {a.x+b1.x+c1.x+d1.x, a.y+b1.y+c1.y+d1.y,
                         a.z+b1.z+c1.z+d1.z, a.w+b1.w+c1.w+d1.w};
            ((float4*)(ws + BQK_OFF))[lane] = s4;
        }
        // beta = bq . bk
        float p = bq[tid] * bk[tid];
#pragma unroll
        for (int m = 32; m; m >>= 1) p += __shfl_xor(p, m, 64);
        __shared__ float bred[4];
        if (lane == 0) bred[wid] = p;
        __syncthreads();
        if (tid == 0) ws[BETA_OFF] = bred[0] + bred[1] + bred[2] + bred[3];
    }
}

// kMain: block (b,i): Xsum from P1; t = Xsum@M + len*bqk; c = Xsum.kvec + len*beta;
// stream 128 rows; block-reduce u,w; project Wv; atomicAdd out.
__global__ void __launch_bounds__(256) kMain(const float* __restrict__ x,
                                             const int* __restrict__ lengths,
                                             const float* __restrict__ ws,
                                             const float* __restrict__ Wv,
                                             const float* __restrict__ bv,
                                             float* __restrict__ out) {
    const int b = blockIdx.y, i = blockIdx.x;
    const int len = lengths[b];
    const int r0 = i * CRP;
    if (r0 >= len) return;                  // whole block exits uniformly
    const int r1 = min(r0 + CRP, len);
    const int tid = threadIdx.x, lane = tid & 63, wid = tid >> 6;

    __shared__ alignas(16) float xs[Ee];
    __shared__ float4 tred[4][64];
    __shared__ float cred[4];
    __shared__ float c_sh;

    // Xsum
    {
        const int nblk = (len + RPB - 1) / RPB;
        const float* P1 = ws + P1_OFF + (size_t)b * BPB * Ee;
        float a = 0.f;
        for (int q = 0; q < nblk; ++q) a += P1[(size_t)q * Ee + tid];
        xs[tid] = a;
    }
    __syncthreads();

    // t: wave wid covers ep in [wid*64, wid*64+64); lane owns e-quad
    {
        const float4* M4 = (const float4*)(ws + M_OFF);
        float4 tacc = {0.f, 0.f, 0.f, 0.f};
#pragma unroll 8
        for (int q = 0; q < 64; ++q) {
            const int ep = wid * 64 + q;
            const float s = xs[ep];
            const float4 m4 = M4[(size_t)ep * E4 + lane];
            tacc.x += s * m4.x; tacc.y += s * m4.y;
            tacc.z += s * m4.z; tacc.w += s * m4.w;
        }
        tred[wid][lane] = tacc;
    }
    // c partial
    {
        float p = xs[tid] * ws[KV_OFF + tid];
#pragma unroll
        for (int m = 32; m; m >>= 1) p += __shfl_xor(p, m, 64);
        if (lane == 0) cred[wid] = p;
    }
    __syncthreads();
    if (tid == 0) c_sh = cred[0] + cred[1] + cred[2] + cred[3] + (float)len * ws[BETA_OFF];
    float4 tv;
    {
        float4 a = tred[0][lane], b1 = tred[1][lane], c1 = tred[2][lane], d1 = tred[3][lane];
        const float4 bqk4 = ((const float4*)(ws + BQK_OFF))[lane];
        tv.x = a.x+b1.x+c1.x+d1.x + (float)len * bqk4.x;
        tv.y = a.y+b1.y+c1.y+d1.y + (float)len * bqk4.y;
        tv.z = a.z+b1.z+c1.z+d1.z + (float)len * bqk4.z;
        tv.w = a.w+b1.w+c1.w+d1.w + (float)len * bqk4.w;
    }
    __syncthreads();
    const float cb = c_sh;

    // stream rows
    const float4* xb = (const float4*)(x + (size_t)b * Ll * Ee);
    float4 uacc = {0.f, 0.f, 0.f, 0.f};
    float wacc = 0.f;
    for (int r = r0 + wid; r < r1; r += 4) {
        float4 xv = xb[(size_t)r * E4 + lane];
        float d = xv.x*tv.x + xv.y*tv.y + xv.z*tv.z + xv.w*tv.w;
#pragma unroll
        for (int m = 32; m; m >>= 1) d += __shfl_xor(d, m, 64);
        float w = d + cb;
        uacc.x += w*xv.x; uacc.y += w*xv.y; uacc.z += w*xv.z; uacc.w += w*xv.w;
        wacc += w;                           // wave-uniform
    }
    __shared__ float4 part[256];
    __shared__ float cw[4];
    __shared__ alignas(16) float u_sh[Ee];
    __shared__ float w_sh;
    part[tid] = uacc;
    if (lane == 0) cw[wid] = wacc;
    __syncthreads();
    if (tid < 64) {
        float4 a = part[tid], b1 = part[64+tid], c1 = part[128+tid], d1 = part[192+tid];
        float4 s4 = {a.x+b1.x+c1.x+d1.x, a.y+b1.y+c1.y+d1.y,
                     a.z+b1.z+c1.z+d1.z, a.w+b1.w+c1.w+d1.w};
        ((float4*)u_sh)[tid] = s4;
    }
    if (tid == 0) w_sh = cw[0] + cw[1] + cw[2] + cw[3];
    __syncthreads();

    // out[b,:] += (Wv . u_i + bv * w_i) / L
    const float4* wrow = (const float4*)(Wv + (size_t)tid * Ee);
    const float4* u4   = (const float4*)u_sh;
    float acc = 0.f;
#pragma unroll 8
    for (int q = 0; q < E4; ++q) {
        float4 w = wrow[q]; float4 v = u4[q];
        acc += w.x*v.x + w.y*v.y + w.z*v.z + w.w*v.w;
    }
    atomicAdd(out + b * Ee + tid, (acc + bv[tid] * w_sh) * (1.0f / (float)Ll));
}

extern "C" void kernel_launch(void* const* d_in, const int* in_sizes, int n_in,
                              void* d_out, int out_size, void* d_ws, size_t ws_size,
                              hipStream_t stream) {
    const float* x       = (const float*)d_in[0];
    const int*   lengths = (const int*)d_in[1];
    const float* Wq      = (const float*)d_in[2];
    const float* bq      = (const float*)d_in[3];
    const float* Wk      = (const float*)d_in[4];
    const float* bk      = (const float*)d_in[5];
    const float* Wv      = (const float*)d_in[6];
    const float* bv      = (const float*)d_in[7];
    float* out = (float*)d_out;
    float* ws  = (float*)d_ws;

    kPrep<<<Bb * BPB + Ee, 256, 0, stream>>>(x, lengths, Wq, bq, Wk, bk, ws, out);
    kMain<<<dim3(CBP, Bb), 256, 0, stream>>>(x, lengths, ws, Wv, bv, out);
}

// Round 8
// 31.659 us; speedup vs baseline: 1.6337x; 1.5988x over previous
//
#include <hip/hip_runtime.h>

#define Bb 16
#define Ll 2048
#define Ee 256
#define E4 64
#define BPB 32          // k1/k3 blocks per batch (64 rows each)
#define RPB 64
#define JT 16           // k2 blocks per batch (t f-slices)
#define FS (Ee / JT)

// ws layout (floats). k1 writes ALL P1 slots (zeros when inactive) so k2's
// reduction is a fixed-count loop. U/W zeroed by k2 (ordered by dispatch).
#define P1_OFF 0                        // [16][32][256] row-sum partials
#define TP_OFF (P1_OFF + Bb*BPB*Ee)     // [16][16][256] t partials
#define C_OFF  (TP_OFF + Bb*JT*Ee)      // [16] c
#define U_OFF  (C_OFF + Bb)             // [16][256] u accumulator
#define W_OFF  (U_OFF + Bb*Ee)          // [16] W accumulator

// k1: partial sums of rows [i*64, i*64+64) with validity masking -> P1[b][i][:].
// Fixed 16-iter unrolled loop: all loads independent, deep pipeline.
__global__ void __launch_bounds__(256) k1(const float* __restrict__ x,
                                          const int* __restrict__ lengths,
                                          float* __restrict__ P1) {
    const int b = blockIdx.y, i = blockIdx.x;
    const int tid = threadIdx.x, lane = tid & 63, wid = tid >> 6;
    const int len = lengths[b];
    const int r0 = i * RPB;
    float4* slot = (float4*)(P1 + ((size_t)(b * BPB + i)) * Ee);
    if (r0 >= len) {                       // inactive: publish zeros, no loads
        if (tid < 64) slot[tid] = make_float4(0.f, 0.f, 0.f, 0.f);
        return;
    }
    const float4* xb = (const float4*)(x + (size_t)b * Ll * Ee);
    float4 acc = {0.f, 0.f, 0.f, 0.f};
#pragma unroll
    for (int rr = 0; rr < 16; ++rr) {
        const int r = r0 + wid + rr * 4;
        float4 v = xb[(size_t)r * E4 + lane];          // padded rows always valid memory
        const bool ok = (r < len);
        acc.x += ok ? v.x : 0.f; acc.y += ok ? v.y : 0.f;
        acc.z += ok ? v.z : 0.f; acc.w += ok ? v.w : 0.f;
    }
    __shared__ float4 part[256];
    part[tid] = acc;
    __syncthreads();
    if (tid < 64) {
        float4 a = part[tid], b1 = part[64+tid], c1 = part[128+tid], d1 = part[192+tid];
        slot[tid] = make_float4(a.x+b1.x+c1.x+d1.x, a.y+b1.y+c1.y+d1.y,
                                a.z+b1.z+c1.z+d1.z, a.w+b1.w+c1.w+d1.w);
    }
}

// k2: block (b,j): Xsum via fixed-32 unrolled reduce; full s; t-slice j.
// j==0 also emits C and zeroes U/W.
__global__ void __launch_bounds__(256) k2(const float* __restrict__ P1,
                                          const int* __restrict__ lengths,
                                          const float* __restrict__ Wq,
                                          const float* __restrict__ bq,
                                          const float* __restrict__ Wk,
                                          const float* __restrict__ bk,
                                          float* __restrict__ TP, float* __restrict__ C,
                                          float* __restrict__ U, float* __restrict__ W) {
    const int b = blockIdx.y, j = blockIdx.x;
    const int tid = threadIdx.x;
    const int len = lengths[b];
    __shared__ alignas(16) float xs[Ee];
    __shared__ alignas(16) float s_sh[Ee];
    {
        const float* P = P1 + (size_t)b * BPB * Ee + tid;
        float a0 = 0.f, a1 = 0.f, a2 = 0.f, a3 = 0.f;
#pragma unroll
        for (int q = 0; q < BPB; q += 4) {             // 32 independent loads
            a0 += P[(size_t)(q+0) * Ee];
            a1 += P[(size_t)(q+1) * Ee];
            a2 += P[(size_t)(q+2) * Ee];
            a3 += P[(size_t)(q+3) * Ee];
        }
        xs[tid] = (a0 + a1) + (a2 + a3);
    }
    __syncthreads();
    {
        const float4* wrow = (const float4*)(Wq + (size_t)tid * Ee);
        const float4* x4   = (const float4*)xs;
        float acc = 0.f;
#pragma unroll 8
        for (int q = 0; q < E4; ++q) {
            float4 w = wrow[q]; float4 v = x4[q];
            acc += w.x*v.x + w.y*v.y + w.z*v.z + w.w*v.w;
        }
        s_sh[tid] = acc + (float)len * bq[tid];
    }
    __syncthreads();
    float tp = 0.f;
#pragma unroll
    for (int f0 = 0; f0 < FS; ++f0) {
        const int f = j * FS + f0;
        tp += s_sh[f] * Wk[(size_t)f * Ee + tid];
    }
    TP[((size_t)(b * JT + j)) * Ee + tid] = tp;
    if (j == 0) {
        U[b * Ee + tid] = 0.f;
        float p = s_sh[tid] * bk[tid];
#pragma unroll
        for (int m = 32; m; m >>= 1) p += __shfl_xor(p, m, 64);
        __shared__ float cred[4];
        if ((tid & 63) == 0) cred[tid >> 6] = p;
        __syncthreads();
        if (tid == 0) { C[b] = cred[0] + cred[1] + cred[2] + cred[3]; W[b] = 0.f; }
    }
}

// k3: tv from fixed-16 TP reduce; fixed-16 unrolled masked stream over 64 rows;
// block-reduce partial u,w; atomicAdd into U/W.
__global__ void __launch_bounds__(256) k3(const float* __restrict__ x,
                                          const int* __restrict__ lengths,
                                          const float* __restrict__ TP,
                                          const float* __restrict__ C,
                                          float* __restrict__ U, float* __restrict__ W) {
    const int b = blockIdx.y, i = blockIdx.x;
    const int len = lengths[b];
    const int r0 = i * RPB;
    if (r0 >= len) return;                 // contributes nothing (atomics skipped)
    const int tid = threadIdx.x, lane = tid & 63, wid = tid >> 6;
    const float4* tp4 = (const float4*)(TP + (size_t)b * JT * Ee);
    float4 tv = {0.f, 0.f, 0.f, 0.f};
#pragma unroll
    for (int jj = 0; jj < JT; ++jj) {      // 16 independent loads
        float4 t = tp4[jj * E4 + lane];
        tv.x += t.x; tv.y += t.y; tv.z += t.z; tv.w += t.w;
    }
    const float cb = C[b];
    const float4* xb = (const float4*)(x + (size_t)b * Ll * Ee);
    float4 uacc = {0.f, 0.f, 0.f, 0.f};
    float wacc = 0.f;
#pragma unroll
    for (int rr = 0; rr < 16; ++rr) {
        const int r = r0 + wid + rr * 4;
        float4 xv = xb[(size_t)r * E4 + lane];         // padded rows valid memory
        float d = xv.x*tv.x + xv.y*tv.y + xv.z*tv.z + xv.w*tv.w;
#pragma unroll
        for (int m = 32; m; m >>= 1) d += __shfl_xor(d, m, 64);
        float w = (r < len) ? (d + cb) : 0.f;          // mask after reduce
        uacc.x += w*xv.x; uacc.y += w*xv.y; uacc.z += w*xv.z; uacc.w += w*xv.w;
        wacc += w;                                     // wave-uniform
    }
    __shared__ float4 part[256];
    __shared__ float cw[4];
    part[tid] = uacc;
    if (lane == 0) cw[wid] = wacc;
    __syncthreads();
    if (tid < 64) {
        float4 a = part[tid], b1 = part[64+tid], c1 = part[128+tid], d1 = part[192+tid];
        float* ub = U + b * Ee + tid * 4;
        atomicAdd(ub + 0, a.x + b1.x + c1.x + d1.x);
        atomicAdd(ub + 1, a.y + b1.y + c1.y + d1.y);
        atomicAdd(ub + 2, a.z + b1.z + c1.z + d1.z);
        atomicAdd(ub + 3, a.w + b1.w + c1.w + d1.w);
    }
    if (tid == 0) atomicAdd(W + b, cw[0] + cw[1] + cw[2] + cw[3]);
}

// k4: block (b,j): out[b, j*64 + lane]; 4 waves split f; fixed 16-iter dots.
__global__ void __launch_bounds__(256) k4(const float* __restrict__ U,
                                          const float* __restrict__ W,
                                          const float* __restrict__ Wv,
                                          const float* __restrict__ bv,
                                          float* __restrict__ out) {
    const int b = blockIdx.y, j = blockIdx.x;   // j in 0..3
    const int tid = threadIdx.x, lane = tid & 63, wid = tid >> 6;
    __shared__ float4 u4[E4];
    __shared__ float red[4][64];
    if (tid < E4) u4[tid] = ((const float4*)(U + b * Ee))[tid];
    __syncthreads();
    const int e = j * 64 + lane;
    const float4* wv = (const float4*)(Wv + (size_t)e * Ee);
    float acc = 0.f;
#pragma unroll
    for (int q = 0; q < 16; ++q) {
        float4 w = wv[wid * 16 + q]; float4 v = u4[wid * 16 + q];
        acc += w.x*v.x + w.y*v.y + w.z*v.z + w.w*v.w;
    }
    red[wid][lane] = acc;
    __syncthreads();
    if (wid == 0) {
        float r = red[0][lane] + red[1][lane] + red[2][lane] + red[3][lane];
        out[b * Ee + e] = (r + bv[e] * W[b]) * (1.0f / (float)Ll);
    }
}

extern "C" void kernel_launch(void* const* d_in, const int* in_sizes, int n_in,
                              void* d_out, int out_size, void* d_ws, size_t ws_size,
                              hipStream_t stream) {
    const float* x       = (const float*)d_in[0];
    const int*   lengths = (const int*)d_in[1];
    const float* Wq      = (const float*)d_in[2];
    const float* bq      = (const float*)d_in[3];
    const float* Wk      = (const float*)d_in[4];
    const float* bk      = (const float*)d_in[5];
    const float* Wv      = (const float*)d_in[6];
    const float* bv      = (const float*)d_in[7];
    float* out = (float*)d_out;
    float* ws  = (float*)d_ws;

    k1<<<dim3(BPB, Bb), 256, 0, stream>>>(x, lengths, ws + P1_OFF);
    k2<<<dim3(JT, Bb), 256, 0, stream>>>(ws + P1_OFF, lengths, Wq, bq, Wk, bk,
                                         ws + TP_OFF, ws + C_OFF, ws + U_OFF, ws + W_OFF);
    k3<<<dim3(BPB, Bb), 256, 0, stream>>>(x, lengths, ws + TP_OFF, ws + C_OFF,
                                          ws + U_OFF, ws + W_OFF);
    k4<<<dim3(4, Bb), 256, 0, stream>>>(ws + U_OFF, ws + W_OFF, Wv, bv, out);
}